// Round 4
// baseline (977.237 us; speedup 1.0000x reference)
//
#include <hip/hip_runtime.h>

static constexpr float KEHALF = 7.199822675975274f; // 14.399645351950548 / 2

typedef float v4f __attribute__((ext_vector_type(4)));
typedef int   v4i __attribute__((ext_vector_type(4)));

// ---------------------------------------------------------------------------
// Single-pass direct-atomic kernel.
//
// Rationale (R3 post-mortem): the 3-dispatch sort pipeline spends ~180 us in
// phaseA (latency-bound, all pipes <25% busy, 220 cy/pair unexplained) plus
// ~260 us of phaseB+gaps we cannot even see in top-5 counters. Structural
// floor for this op is: stream 256 MB of pairs (~45 us) + 16M f32 atomics
// into a 2 MB L2-resident output (~50-100 us at ~300G RMW/s, overlapped).
// R1's scattered-store regression (2x WRITE_SIZE) was dirty-line eviction in
// a 64 MB streamed recs region; atomics into 2 MB stay L2-resident, so that
// failure mode does not apply -- predicted WRITE_SIZE ~= out size only.
//
// Per pair: 2 coalesced-stream quads in, 2 random 4B Zf gathers (2 MB table,
// L2-hot), 2 LDS LUT reads for z^sp(apow), 4 exp, 1 global f32 atomicAdd.
// ---------------------------------------------------------------------------
__global__ void __launch_bounds__(256)
zbl_direct(const int* __restrict__ idx_i, const int* __restrict__ idx_j,
           const float* __restrict__ rij, const float* __restrict__ cut,
           const float* __restrict__ Zf,
           const float* __restrict__ adiv, const float* __restrict__ apow,
           const float* __restrict__ c1, const float* __restrict__ c2,
           const float* __restrict__ c3, const float* __restrict__ c4,
           const float* __restrict__ a1p, const float* __restrict__ a2p,
           const float* __restrict__ a3p, const float* __restrict__ a4p,
           float* __restrict__ out, int P) {
    __shared__ float lA[96];   // lA[z] = sp(adiv) * z^sp(apow)

    // consts computed redundantly per thread (10 broadcast scalar loads,
    // ~20 transcendentals once per thread per kernel -- negligible)
    auto sp = [](float x) { return log1pf(expf(x)); };
    const float c1p = sp(*c1), c2p = sp(*c2), c3p = sp(*c3), c4p = sp(*c4);
    const float inv = 1.0f / (c1p + c2p + c3p + c4p);
    const float c1n = c1p * inv, c2n = c2p * inv;
    const float c3n = c3p * inv, c4n = c4p * inv;
    const float a1 = sp(*a1p), a2 = sp(*a2p), a3 = sp(*a3p), a4 = sp(*a4p);
    const float sp_apow = sp(*apow), sp_adiv = sp(*adiv);

    if (threadIdx.x < 96)
        lA[threadIdx.x] = (threadIdx.x == 0)
            ? 0.0f
            : sp_adiv * __expf(sp_apow * __logf((float)threadIdx.x));
    __syncthreads();

    const int tid = blockIdx.x * 256 + threadIdx.x;
    const int stride = gridDim.x * 256;
    const int P4 = P >> 2;

    const v4i* ii4 = reinterpret_cast<const v4i*>(idx_i);
    const v4i* jj4 = reinterpret_cast<const v4i*>(idx_j);
    const v4f* rr4 = reinterpret_cast<const v4f*>(rij);
    const v4f* cc4 = reinterpret_cast<const v4f*>(cut);

    for (int q = tid; q < P4; q += stride) {
        v4i ii = __builtin_nontemporal_load(ii4 + q);
        v4i jj = __builtin_nontemporal_load(jj4 + q);
        v4f rr = __builtin_nontemporal_load(rr4 + q);
        v4f cc = __builtin_nontemporal_load(cc4 + q);

        // issue all 8 gathers before consuming any (overlap L2 latency)
        float zfi0 = Zf[ii[0]], zfi1 = Zf[ii[1]],
              zfi2 = Zf[ii[2]], zfi3 = Zf[ii[3]];
        float zfj0 = Zf[jj[0]], zfj1 = Zf[jj[1]],
              zfj2 = Zf[jj[2]], zfj3 = Zf[jj[3]];

        auto body = [&](int i, float zfi, float zfj, float r, float cu) {
            float ar = (lA[(int)zfi] + lA[(int)zfj]) * r;
            float f = c1n * __expf(-a1 * ar) + c2n * __expf(-a2 * ar)
                    + c3n * __expf(-a3 * ar) + c4n * __expf(-a4 * ar);
            atomicAdd(&out[i],
                      KEHALF * f * cu * zfi * zfj * __builtin_amdgcn_rcpf(r));
        };
        body(ii[0], zfi0, zfj0, rr[0], cc[0]);
        body(ii[1], zfi1, zfj1, rr[1], cc[1]);
        body(ii[2], zfi2, zfj2, rr[2], cc[2]);
        body(ii[3], zfi3, zfj3, rr[3], cc[3]);
    }

    // scalar tail (P not multiple of 4)
    if (tid == 0) {
        for (int p = P4 << 2; p < P; ++p) {
            int i = idx_i[p];
            float zfi = Zf[i], zfj = Zf[idx_j[p]];
            float r = rij[p];
            float ar = (lA[(int)zfi] + lA[(int)zfj]) * r;
            float f = c1n * __expf(-a1 * ar) + c2n * __expf(-a2 * ar)
                    + c3n * __expf(-a3 * ar) + c4n * __expf(-a4 * ar);
            atomicAdd(&out[i], KEHALF * f * cut[p] * zfi * zfj *
                               __builtin_amdgcn_rcpf(r));
        }
    }
}

// ---------------------------------------------------------------------------
extern "C" void kernel_launch(void* const* d_in, const int* in_sizes, int n_in,
                              void* d_out, int out_size, void* d_ws, size_t ws_size,
                              hipStream_t stream) {
    // 0:N 1:Zf 2:rij 3:cutoff 4:idx_i 5:idx_j 6:adiv 7:apow 8..11:c 12..15:a
    const float* Zf = (const float*)d_in[1];
    const float* rij = (const float*)d_in[2];
    const float* cut = (const float*)d_in[3];
    const int* idx_i = (const int*)d_in[4];
    const int* idx_j = (const int*)d_in[5];
    const int P = in_sizes[2];
    float* out = (float*)d_out;

    hipMemsetAsync(out, 0, (size_t)out_size * sizeof(float), stream);

    int nblk = (P / 4 + 255) / 256;
    if (nblk < 1) nblk = 1;
    if (nblk > 2048) nblk = 2048;   // grid-stride; ~8 blocks/CU

    zbl_direct<<<nblk, 256, 0, stream>>>(
        idx_i, idx_j, rij, cut, Zf,
        (const float*)d_in[6], (const float*)d_in[7],
        (const float*)d_in[8], (const float*)d_in[9],
        (const float*)d_in[10], (const float*)d_in[11],
        (const float*)d_in[12], (const float*)d_in[13],
        (const float*)d_in[14], (const float*)d_in[15],
        out, P);
}